// Round 1
// baseline (63.276 us; speedup 1.0000x reference)
//
#include <hip/hip_runtime.h>
#include <hip/hip_bf16.h>
#include <cstdint>

#define BB 64
#define CC 256
#define HH 64
#define WW 64
#define EPSF 1e-5f

// ---------------------------------------------------------------------------
// Kernel 0: bounds + counts. One thread per batch element.
// Bit-exact replication of the reference float32 arithmetic: no FMA
// contraction (use __f*_rn intrinsics), floorf, int32 truncation.
// bnds layout: [b][bank][ r0[3], r1[3], c0[3], c1[3] ]  (48 ints per b)
// cntf layout: [b][bank*9 + i*3 + j]  (36 floats per b)
// ---------------------------------------------------------------------------
__device__ __forceinline__ void subj_bounds_dev(float y0, float y1, float x0, float x1,
                                                int* dst /*12*/) {
    float ch = __fdiv_rn(__fsub_rn(y1, y0), 3.0f);
    float cw = __fdiv_rn(__fsub_rn(x1, x0), 3.0f);
    for (int i = 0; i < 3; ++i) {
        float fi = (float)i;
        int R0 = (int)floorf(__fmul_rn((float)HH, __fadd_rn(y0, __fmul_rn(fi, ch))));
        int R1 = (int)floorf(__fmul_rn((float)HH, __fadd_rn(y0, __fmul_rn(__fadd_rn(fi, 1.0f), ch))));
        bool dr = (R1 <= R0);
        int R1n = (dr && (R1 < HH - 1)) ? R1 + 1 : R1;
        int R0n = (dr && (R1 >= HH - 1)) ? R0 - 1 : R0;
        int C0 = (int)floorf(__fmul_rn((float)WW, __fadd_rn(x0, __fmul_rn(fi, cw))));
        int C1 = (int)floorf(__fmul_rn((float)WW, __fadd_rn(x0, __fmul_rn(__fadd_rn(fi, 1.0f), cw))));
        bool dc = (C1 <= C0);
        int C1n = (dc && (C1 < WW)) ? C1 + 1 : C1;
        int C0n = (dc && (C1 >= WW)) ? C0 - 1 : C0;
        dst[i]     = R0n;
        dst[3 + i] = R1n;
        dst[6 + i] = C0n;
        dst[9 + i] = C1n;
    }
}

__device__ __forceinline__ void joint_bounds_dev(float uy0, float uy1, float ux0, float ux1,
                                                 float by0, float by1, float bx0, float bx1,
                                                 int* dst /*12*/) {
    float ch = __fdiv_rn(__fsub_rn(uy1, uy0), 3.0f);
    float cw = __fdiv_rn(__fsub_rn(ux1, ux0), 3.0f);
    for (int i = 0; i < 3; ++i) {
        float fi = (float)i;
        float ylo = __fadd_rn(uy0, __fmul_rn(fi, ch));
        float yhi = __fadd_rn(uy0, __fmul_rn(__fadd_rn(fi, 1.0f), ch));
        float xlo = __fadd_rn(ux0, __fmul_rn(fi, cw));
        float xhi = __fadd_rn(ux0, __fmul_rn(__fadd_rn(fi, 1.0f), cw));
        dst[i]     = (int)floorf(__fmul_rn((float)HH, fmaxf(by0, ylo)));
        dst[3 + i] = (int)floorf(__fmul_rn((float)HH, fminf(by1, yhi)));
        dst[6 + i] = (int)floorf(__fmul_rn((float)WW, fmaxf(bx0, xlo)));
        dst[9 + i] = (int)floorf(__fmul_rn((float)WW, fminf(bx1, xhi)));
    }
}

__global__ void k_bounds(const float* __restrict__ bbox_s,
                         const float* __restrict__ bbox_o,
                         int* __restrict__ bnds,
                         float* __restrict__ cntf) {
    int b = blockIdx.x * blockDim.x + threadIdx.x;
    if (b >= BB) return;
    float sy0 = bbox_s[b * 4 + 0], sy1 = bbox_s[b * 4 + 1];
    float sx0 = bbox_s[b * 4 + 2], sx1 = bbox_s[b * 4 + 3];
    float oy0 = bbox_o[b * 4 + 0], oy1 = bbox_o[b * 4 + 1];
    float ox0 = bbox_o[b * 4 + 2], ox1 = bbox_o[b * 4 + 3];

    int loc[4][12];
    subj_bounds_dev(sy0, sy1, sx0, sx1, loc[0]);
    subj_bounds_dev(oy0, oy1, ox0, ox1, loc[1]);
    float uy0 = fminf(sy0, oy0), uy1 = fmaxf(sy1, oy1);
    float ux0 = fminf(sx0, ox0), ux1 = fmaxf(sx1, ox1);
    joint_bounds_dev(uy0, uy1, ux0, ux1, sy0, sy1, sx0, sx1, loc[2]);
    joint_bounds_dev(uy0, uy1, ux0, ux1, oy0, oy1, ox0, ox1, loc[3]);

    int* ob = bnds + b * 48;
    float* oc = cntf + b * 36;
    for (int bank = 0; bank < 4; ++bank) {
        for (int q = 0; q < 12; ++q) ob[bank * 12 + q] = loc[bank][q];
        for (int i = 0; i < 3; ++i) {
            int rl = max(loc[bank][i], 0);
            int rh = min(loc[bank][3 + i], HH);
            int nrows = max(0, rh - rl);
            for (int j = 0; j < 3; ++j) {
                int cl = max(loc[bank][6 + j], 0);
                int chh = min(loc[bank][9 + j], WW);
                int ncols = max(0, chh - cl);
                oc[bank * 9 + i * 3 + j] = (float)(nrows * ncols);
            }
        }
    }
}

// ---------------------------------------------------------------------------
// Kernel 1: per-(b,c) plane 2D prefix sum in LDS -> 36 region sums.
// One wave (64 threads) per block. [64][65] padding: 65 mod 32 == 1, so both
// row scan (lane=row) and column scan (lane=col) are bank-conflict-free.
// M layout: [b][c][36]  (stores raw region SUMS; head kernel divides by cnt)
// ---------------------------------------------------------------------------
__global__ __launch_bounds__(64) void k_region_sums(const float* __restrict__ feat,
                                                    const int* __restrict__ bnds,
                                                    float* __restrict__ M) {
    int b = blockIdx.x >> 8;
    int c = blockIdx.x & 255;
    int l = threadIdx.x;

    __shared__ float S[64 * 65];

    const float4* src = (const float4*)(feat + ((size_t)(b * CC + c)) * (HH * WW));
    // load plane (coalesced float4)
    for (int it = 0; it < 16; ++it) {
        int f = it * 256 + l * 4;
        int h = f >> 6, w = f & 63;
        float4 v = src[it * 64 + l];
        float* dst = &S[h * 65 + w];
        dst[0] = v.x; dst[1] = v.y; dst[2] = v.z; dst[3] = v.w;
    }
    __syncthreads();

    // row prefix: lane l scans row l
    {
        float run = 0.0f;
        int base = l * 65;
        for (int i = 0; i < 64; ++i) { run += S[base + i]; S[base + i] = run; }
    }
    __syncthreads();

    // col prefix: lane l scans column l
    {
        float run = 0.0f;
        for (int i = 0; i < 64; ++i) { run += S[i * 65 + l]; S[i * 65 + l] = run; }
    }
    __syncthreads();

    // region eval: lanes 0..35, each region = 4 LDS lookups
    if (l < 36) {
        const int* bk = bnds + b * 48 + (l / 9) * 12;
        int ij = l % 9, i = ij / 3, j = ij % 3;
        int r0 = bk[i], r1 = bk[3 + i], c0 = bk[6 + j], c1 = bk[9 + j];
        int rl = max(r0, 0), rh = min(r1, HH);
        int cl = max(c0, 0), chh = min(c1, WW);
        float s = 0.0f;
        if (rh > rl && chh > cl) {
            float a = S[(rh - 1) * 65 + (chh - 1)];
            float q = (cl > 0) ? S[(rh - 1) * 65 + (cl - 1)] : 0.0f;
            float p = (rl > 0) ? S[(rl - 1) * 65 + (chh - 1)] : 0.0f;
            float d = (rl > 0 && cl > 0) ? S[(rl - 1) * 65 + (cl - 1)] : 0.0f;
            s = a - q - p + d;
        }
        M[((size_t)(b * CC + c)) * 36 + l] = s;
    }
}

// ---------------------------------------------------------------------------
// Kernel 2: head. One block per b. Stage M[b] (256x36) in LDS (pad 37),
// 324 threads each dot 256 channels with conv_w row, BN2 + zero-count mask,
// fold 4 banks -> f[81], then 81->40->9 MLP + predicate dot.
// ---------------------------------------------------------------------------
__global__ __launch_bounds__(384) void k_head(const float* __restrict__ M,
                                              const float* __restrict__ cntf,
                                              const float* __restrict__ conv_w,
                                              const float* __restrict__ conv_b,
                                              const float* __restrict__ g2,
                                              const float* __restrict__ b2,
                                              const float* __restrict__ m2,
                                              const float* __restrict__ v2,
                                              const float* __restrict__ fc1_w,
                                              const float* __restrict__ fc1_b,
                                              const float* __restrict__ g1,
                                              const float* __restrict__ b1,
                                              const float* __restrict__ m1,
                                              const float* __restrict__ v1,
                                              const float* __restrict__ fc2_w,
                                              const float* __restrict__ fc2_b,
                                              const float* __restrict__ pred,
                                              float* __restrict__ out) {
    int b = blockIdx.x;
    int t = threadIdx.x;

    __shared__ float Ml[256 * 37];
    __shared__ float val[324];
    __shared__ float fv[81];
    __shared__ float hv[40];
    __shared__ float lg[9];

    // stage M[b] (coalesced read, padded LDS write)
    for (int i = t; i < 256 * 36; i += 384) {
        int c = i / 36, r = i - c * 36;
        Ml[c * 37 + r] = M[(size_t)b * (256 * 36) + i];
    }
    __syncthreads();

    if (t < 324) {
        int region = t / 9, k = t - region * 9;
        int bank = region / 9, ij = region - bank * 9;
        int ii = ij / 3, jj = ij % 3;
        int o = bank * 81 + ii * 27 + jj * 9 + k;
        float cnt = cntf[b * 36 + region];
        float v = 0.0f;
        if (cnt > 0.0f) {
            const float* w = conv_w + o * 256;
            float dot = 0.0f;
            #pragma unroll 8
            for (int c = 0; c < 256; ++c) dot += w[c] * Ml[c * 37 + region];
            float mean = dot / cnt;
            float sc = g2[o] / sqrtf(v2[o] + EPSF);
            v = (mean + conv_b[o] - m2[o]) * sc + b2[o];
        }
        val[region * 9 + k] = v;
    }
    __syncthreads();

    // f[k*9 + i*3 + j] = sum over 4 banks
    if (t < 81) {
        int k = t / 9, ij = t - k * 9;
        fv[t] = val[(0 + ij) * 9 + k] + val[(9 + ij) * 9 + k] +
                val[(18 + ij) * 9 + k] + val[(27 + ij) * 9 + k];
    }
    __syncthreads();

    if (t < 40) {
        float h = fc1_b[t];
        for (int u = 0; u < 81; ++u) h += fv[u] * fc1_w[t * 81 + u];
        h = (h - m1[t]) * (g1[t] / sqrtf(v1[t] + EPSF)) + b1[t];
        hv[t] = h;
    }
    __syncthreads();

    if (t < 9) {
        float lgt = fc2_b[t];
        for (int u = 0; u < 40; ++u) lgt += hv[u] * fc2_w[t * 40 + u];
        lg[t] = lgt * pred[b * 9 + t];
    }
    __syncthreads();

    if (t == 0) {
        float s = 0.0f;
        for (int i = 0; i < 9; ++i) s += lg[i];
        out[b] = s;
    }
}

extern "C" void kernel_launch(void* const* d_in, const int* in_sizes, int n_in,
                              void* d_out, int out_size, void* d_ws, size_t ws_size,
                              hipStream_t stream) {
    const float* feat   = (const float*)d_in[0];
    const float* bbox_s = (const float*)d_in[1];
    const float* bbox_o = (const float*)d_in[2];
    const float* pred   = (const float*)d_in[3];
    const float* conv_w = (const float*)d_in[4];
    const float* conv_b = (const float*)d_in[5];
    const float* g2     = (const float*)d_in[6];
    const float* b2     = (const float*)d_in[7];
    const float* m2     = (const float*)d_in[8];
    const float* v2     = (const float*)d_in[9];
    const float* fc1_w  = (const float*)d_in[10];
    const float* fc1_b  = (const float*)d_in[11];
    const float* g1     = (const float*)d_in[12];
    const float* b1     = (const float*)d_in[13];
    const float* m1     = (const float*)d_in[14];
    const float* v1     = (const float*)d_in[15];
    const float* fc2_w  = (const float*)d_in[16];
    const float* fc2_b  = (const float*)d_in[17];
    float* out = (float*)d_out;

    char* ws = (char*)d_ws;
    int*   bnds = (int*)ws;                    // 64*48*4   = 12288 B
    float* cntf = (float*)(ws + 12288);        // 64*36*4   =  9216 B
    float* M    = (float*)(ws + 32768);        // 64*256*36*4 = 2359296 B

    k_bounds<<<1, 64, 0, stream>>>(bbox_s, bbox_o, bnds, cntf);
    k_region_sums<<<BB * CC, 64, 0, stream>>>(feat, bnds, M);
    k_head<<<BB, 384, 0, stream>>>(M, cntf, conv_w, conv_b, g2, b2, m2, v2,
                                   fc1_w, fc1_b, g1, b1, m1, v1, fc2_w, fc2_b,
                                   pred, out);
}